// Round 3
// baseline (402.968 us; speedup 1.0000x reference)
//
#include <hip/hip_runtime.h>

// DayAdapter: out[b,t,e] = softsign( x[b,t,:] @ W[day[b]] + bias[day[b]] )
// x: [64,1024,512] f32, day_ids: [64] i32, W: [24,512,512] f32, bias: [24,512] f32
//
// Round 5: panel-resident B, barrier-free streaming loop.
// R3/R4 post-mortem: the barrier-per-K-step structure caps per-CU vmem
// throughput (~21 GB/s/CU) regardless of occupancy (R4: more waves -> MORE
// traffic, worse) or per-wave pipelining (R3: +28%/block, eaten by occupancy).
// Fix the structure: W[day] panel (128 cols x 512 k = 128 KB bf16) fits LDS.
//   grid = 256 blocks (64 b x 4 g), 1024 threads = 16 waves = 1 block/CU.
//   Stage panel once (swizzled gll16), ONE barrier, then stream:
//   x -> regs (f32->bf16 inline), B from read-only LDS, MFMA, store.
//   No barriers in the loop -> continuous issue, no vmcnt drains.
//   B staged once per block (was 8x per block at BK=64) -> staging bytes/block
//   786KB -> 128KB. A-path ds_writes eliminated -> bank conflicts ~0.
// LDS swizzle: granule row = 65x16B (pad); chunk c=(kc,q) stored at
//   cp = (16q + kc + 4n) & 63 -> bank = (5n + 16q + kc) % 32 -> exactly 2-way
//   across lanes (free per m136). gll16 dest stays lane-linear (wave-uniform
//   base + lane*16); the permutation is applied to the per-lane GLOBAL source.
// XCD swizzle: L&7 = b%8 -> the 4 g-panels of one b co-run on one XCD's L2.

#define DIM 512
#define SEQ 1024
#define NDAYS 24
#define BN 128          // panel width (cols) per block
#define GRAN16 65       // 16B granules per LDS row: 64 data + 1 pad

typedef __bf16 bf16x8 __attribute__((ext_vector_type(8)));
typedef float  f32x4  __attribute__((ext_vector_type(4)));

__device__ __forceinline__ void gll16(const void* g, void* l) {
    __builtin_amdgcn_global_load_lds(
        (const __attribute__((address_space(1))) unsigned int*)g,
        (__attribute__((address_space(3))) unsigned int*)l,
        16, 0, 0);
}

// ---- kernel 1: Wt[d][n][k] = bf16(W[d][k][n]) ----
__global__ __launch_bounds__(256)
void transpose_w_kernel(const float* __restrict__ W, __bf16* __restrict__ Wt) {
    __shared__ __bf16 T[32][33];
    const int d  = blockIdx.z;
    const int k0 = blockIdx.x * 32;
    const int n0 = blockIdx.y * 32;
    const int tx = threadIdx.x & 31;
    const int ty = threadIdx.x >> 5;   // 0..7
    const float* Wd = W + (size_t)d * DIM * DIM;
    #pragma unroll
    for (int i = 0; i < 4; ++i) {
        const int k = ty + i * 8;
        T[tx][k] = (__bf16)Wd[(size_t)(k0 + k) * DIM + n0 + tx];  // coalesced f32 read
    }
    __syncthreads();
    __bf16* Wtd = Wt + (size_t)d * DIM * DIM;
    #pragma unroll
    for (int i = 0; i < 4; ++i) {
        const int n = ty + i * 8;
        Wtd[(size_t)(n0 + n) * DIM + k0 + tx] = T[n][tx];         // coalesced bf16 write
    }
}

// ---- kernel 2: panel-resident GEMM + bias + softsign ----
__global__ __launch_bounds__(1024, 4)
void day_adapter_kernel(const float* __restrict__ x,
                        const int*   __restrict__ day_ids,
                        const __bf16* __restrict__ Wt,
                        const float* __restrict__ bias,
                        float*       __restrict__ out)
{
    __shared__ __align__(16) char Bs[BN * GRAN16 * 16];   // 133120 B

    // XCD mapping: L = (b%8) + 8*(g + 4*(b/8)); bijective over 256 blocks.
    const int L   = blockIdx.x;
    const int h   = L >> 3;            // 0..31
    const int g   = h & 3;             // panel 0..3
    const int bb  = (L & 7) + 8 * (h >> 2);

    const int tid  = threadIdx.x;
    const int wave = tid >> 6;         // 0..15
    const int lane = tid & 63;
    const int l15  = lane & 15;
    const int quad = lane >> 4;        // 0..3

    const int day = day_ids[bb];
    const __bf16* Wtb = Wt  + (size_t)day * DIM * DIM + (size_t)(g * BN) * DIM;
    const float*  xb  = x   + (size_t)bb  * SEQ * DIM;
    float*        ob  = out + (size_t)bb  * SEQ * DIM + g * BN;
    const float*  bd  = bias + (size_t)day * DIM + g * BN;

    // ---- stage panel: 128 rows x 64 granules, once ----
    // Slot (n, cp=lane) holds chunk c solving cp = (16q + kc + 4n)&63:
    //   t = (cp - 4n)&63; kc = t&15; q = t>>4; c = 4*kc + q.
    #pragma unroll
    for (int it = 0; it < 8; ++it) {
        const int n = it * 16 + wave;                 // wave-uniform row
        const int t = (lane - 4 * n) & 63;
        const int c = ((t & 15) << 2) | (t >> 4);
        gll16(Wtb + (size_t)n * DIM + c * 8,          // per-lane global source
              Bs + n * (GRAN16 * 16));                // lane-linear LDS dest
    }
    __syncthreads();   // the only barrier

    // ---- streaming: wave owns rows [wave*64, wave*64+64), 2 chunks of 32 ----
    #pragma unroll
    for (int ch = 0; ch < 2; ++ch) {
        const int r0 = wave * 64 + ch * 32;

        f32x4 acc[2][8];
        const f32x4 zero = {0.f, 0.f, 0.f, 0.f};
        #pragma unroll
        for (int i = 0; i < 2; ++i)
            #pragma unroll
            for (int j = 0; j < 8; ++j) acc[i][j] = zero;

        #pragma unroll
        for (int kc = 0; kc < 16; ++kc) {
            // A: 2 frags direct global->reg, f32 -> bf16
            bf16x8 af[2];
            #pragma unroll
            for (int i = 0; i < 2; ++i) {
                const float* p = xb + (size_t)(r0 + i * 16 + l15) * DIM
                                    + kc * 32 + quad * 8;
                const float4 f0 = *(const float4*)p;
                const float4 f1 = *(const float4*)(p + 4);
                bf16x8 v;
                v[0] = (__bf16)f0.x; v[1] = (__bf16)f0.y;
                v[2] = (__bf16)f0.z; v[3] = (__bf16)f0.w;
                v[4] = (__bf16)f1.x; v[5] = (__bf16)f1.y;
                v[6] = (__bf16)f1.z; v[7] = (__bf16)f1.w;
                af[i] = v;
            }
            // B: 8 n-frags from LDS (read-only, swizzled, conflict-free)
            #pragma unroll
            for (int j = 0; j < 8; ++j) {
                const int n  = j * 16 + l15;
                const int cp = (quad * 16 + kc + 4 * n) & 63;
                const bf16x8 bv = *(const bf16x8*)(Bs + n * (GRAN16 * 16) + cp * 16);
                acc[0][j] = __builtin_amdgcn_mfma_f32_16x16x32_bf16(af[0], bv, acc[0][j], 0, 0, 0);
                acc[1][j] = __builtin_amdgcn_mfma_f32_16x16x32_bf16(af[1], bv, acc[1][j], 0, 0, 0);
            }
        }

        // epilogue: bias + softsign, per chunk
        #pragma unroll
        for (int j = 0; j < 8; ++j) {
            const float bvj = bd[j * 16 + l15];
            #pragma unroll
            for (int i = 0; i < 2; ++i) {
                const int rbase = r0 + i * 16 + quad * 4;   // C/D: row = quad*4 + reg
                #pragma unroll
                for (int r = 0; r < 4; ++r) {
                    const float y = acc[i][j][r] + bvj;
                    ob[(size_t)(rbase + r) * DIM + j * 16 + l15] = y / (1.0f + fabsf(y));
                }
            }
        }
    }
}

extern "C" void kernel_launch(void* const* d_in, const int* in_sizes, int n_in,
                              void* d_out, int out_size, void* d_ws, size_t ws_size,
                              hipStream_t stream) {
    const float* x       = (const float*)d_in[0];
    const int*   day_ids = (const int*)  d_in[1];
    const float* W       = (const float*)d_in[2];
    const float* bias    = (const float*)d_in[3];
    float*       out     = (float*)d_out;
    __bf16*      Wt      = (__bf16*)d_ws;   // 24*512*512*2 = 12.58 MB

    dim3 tgrid(DIM / 32, DIM / 32, NDAYS);  // (16,16,24)
    transpose_w_kernel<<<tgrid, 256, 0, stream>>>(W, Wt);

    day_adapter_kernel<<<dim3(256), 1024, 0, stream>>>(x, day_ids, Wt, bias, out);
}

// Round 4
// 311.123 us; speedup vs baseline: 1.2952x; 1.2952x over previous
//
#include <hip/hip_runtime.h>

// DayAdapter: out[b,t,e] = softsign( x[b,t,:] @ W[day[b]] + bias[day[b]] )
// x: [64,1024,512] f32, day_ids: [64] i32, W: [24,512,512] f32, bias: [24,512] f32
//
// Round 6: HBM segment-density attack on the R2 skeleton (best, 99us main).
// Post-mortem synthesis R0-R5: service rate invariant at 3.2-3.3 TB/s across
// occupancy 28-49% and pipeline depth 0-2 => latency-equilibrium with a pattern-
// limited service rate, not an occupancy/ILP problem. The two sparse streams:
//   (a) A-staging map issued 16 x 64B segments @2KB stride per load instr;
//   (b) epilogue issued 256 scattered 64B stores per wave.
// Fix (only change vs R2):
//   (a) row-linear A map: row=s>>4, col=(s&15)*4 -> 4 rows x 256B dense per
//       instr; bf16x4 LDS writes stay bank-uniform (4/bank = min cycles).
//   (b) epilogue transposes through per-wave private LDS scratch (reuses dead
//       As, stride 68 f32 = 16B-aligned rows, bank-uniform write 2-way/read 8min)
//       -> float4 stores, 4 rows x 256B dense per instr. No barriers needed.
// (SQ_LDS_BANK_CONFLICT==2^22 across R0-R4 = width-replay of 2^20 b128 frag
//  reads; irreducible, not a target.)

#define DIM 512
#define SEQ 1024
#define NB 64
#define NDAYS 24
#define BM 128
#define BN 128
#define BK 64
#define LDA (BK + 8)   // A row stride (bf16): 144B, 16B-aligned

typedef __bf16 bf16x8 __attribute__((ext_vector_type(8)));
typedef __bf16 bf16x4 __attribute__((ext_vector_type(4)));
typedef float  f32x4  __attribute__((ext_vector_type(4)));

__device__ __forceinline__ void gll16(const void* g, void* l) {
    __builtin_amdgcn_global_load_lds(
        (const __attribute__((address_space(1))) unsigned int*)g,
        (__attribute__((address_space(3))) unsigned int*)l,
        16, 0, 0);
}

// ---- kernel 1: Wt[d][n][k] = bf16(W[d][k][n]) ----
__global__ __launch_bounds__(256)
void transpose_w_kernel(const float* __restrict__ W, __bf16* __restrict__ Wt) {
    __shared__ __bf16 T[32][33];
    const int d  = blockIdx.z;
    const int k0 = blockIdx.x * 32;
    const int n0 = blockIdx.y * 32;
    const int tx = threadIdx.x & 31;
    const int ty = threadIdx.x >> 5;   // 0..7
    const float* Wd = W + (size_t)d * DIM * DIM;
    #pragma unroll
    for (int i = 0; i < 4; ++i) {
        const int k = ty + i * 8;
        T[tx][k] = (__bf16)Wd[(size_t)(k0 + k) * DIM + n0 + tx];  // coalesced f32 read
    }
    __syncthreads();
    __bf16* Wtd = Wt + (size_t)d * DIM * DIM;
    #pragma unroll
    for (int i = 0; i < 4; ++i) {
        const int n = ty + i * 8;
        Wtd[(size_t)(n0 + n) * DIM + k0 + tx] = T[n][tx];         // coalesced bf16 write
    }
}

// ---- kernel 2: main GEMM + bias + softsign ----
__global__ __launch_bounds__(256, 4)
void day_adapter_kernel(const float* __restrict__ x,
                        const int*   __restrict__ day_ids,
                        const __bf16* __restrict__ Wt,
                        const float* __restrict__ bias,
                        float*       __restrict__ out)
{
    __shared__ __align__(16) __bf16 As[BM][LDA];    // 128 x 72 bf16 = 18432 B
    __shared__ __align__(16) __bf16 Bs[BN * BK];    // 16384 B, swizzled 16B chunks

    // XCD swizzle: L = xcdslot(3b) | ntile(2b) | hi(6b); the 4 ntiles of one
    // (m,b) share L mod 8 -> same XCD under round-robin dispatch.
    const int L  = blockIdx.x;
    const int g  = (L >> 3) & 3;
    const int mb = (L & 7) | ((L >> 5) << 3);   // 0..511
    const int m  = mb & 7;
    const int bb = mb >> 3;

    const int n0  = g * BN;
    const int m0  = m * BM;
    const int tid = threadIdx.x;
    const int day = day_ids[bb];

    const float*  xb  = x   + (size_t)bb  * SEQ * DIM + (size_t)m0 * DIM;
    const __bf16* Wtb = Wt  + (size_t)day * DIM * DIM + (size_t)n0 * DIM;
    float*        ob  = out + (size_t)bb  * SEQ * DIM + (size_t)m0 * DIM + n0;

    const int wave = tid >> 6;
    const int lane = tid & 63;
    const int wm   = (wave >> 1) * 64;
    const int wn   = (wave & 1) * 64;
    const int l15  = lane & 15;
    const int quad = lane >> 4;          // 0..3
    const int kq   = quad * 8;

    char* BsB = (char*)Bs;

    f32x4 acc[4][4];
    const f32x4 zero = {0.f, 0.f, 0.f, 0.f};
    #pragma unroll
    for (int i = 0; i < 4; ++i)
        #pragma unroll
        for (int j = 0; j < 4; ++j) acc[i][j] = zero;

    for (int kk = 0; kk < DIM; kk += BK) {
        // -- B: async global->LDS, 4 x 16B per thread, swizzled chunk placement --
        #pragma unroll
        for (int p = 0; p < 4; ++p) {
            const int s  = p * 256 + tid;
            const int n  = s >> 3;
            const int cp = s & 7;
            const int c  = cp ^ (n & 7);
            gll16(Wtb + (size_t)n * DIM + kk + c * 8,
                  BsB + (size_t)(p * 256 + (tid & ~63)) * 16);
        }
        // -- A: row-linear staging: per instr = 4 rows x 256B dense global reads --
        #pragma unroll
        for (int p = 0; p < 8; ++p) {
            const int s   = p * 256 + tid;
            const int row = s >> 4;             // 16 threads x 16B = full 256B row
            const int col = (s & 15) * 4;
            const float4 f = *(const float4*)(xb + (size_t)row * DIM + kk + col);
            bf16x4 v;
            v[0] = (__bf16)f.x; v[1] = (__bf16)f.y;
            v[2] = (__bf16)f.z; v[3] = (__bf16)f.w;
            *(bf16x4*)&As[row][col] = v;
        }
        __syncthreads();

        #pragma unroll
        for (int ks = 0; ks < 2; ++ks) {
            bf16x8 af[4], bfr[4];
            #pragma unroll
            for (int i = 0; i < 4; ++i)
                af[i] = *(const bf16x8*)&As[wm + i * 16 + l15][ks * 32 + kq];
            #pragma unroll
            for (int j = 0; j < 4; ++j) {
                const int n  = wn + j * 16 + l15;
                const int c  = ks * 4 + quad;
                const int cp = c ^ (n & 7);
                bfr[j] = *(const bf16x8*)&Bs[n * BK + cp * 8];
            }
            #pragma unroll
            for (int i = 0; i < 4; ++i)
                #pragma unroll
                for (int j = 0; j < 4; ++j)
                    acc[i][j] = __builtin_amdgcn_mfma_f32_16x16x32_bf16(
                        af[i], bfr[j], acc[i][j], 0, 0, 0);
        }
        __syncthreads();
    }
    // final __syncthreads above: all waves done with As/Bs -> safe to reuse As.

    // -- epilogue: bias + softsign, transposed through per-wave LDS scratch --
    float bv[4];
    #pragma unroll
    for (int j = 0; j < 4; ++j)
        bv[j] = bias[(size_t)day * DIM + n0 + wn + j * 16 + l15];

    // per-wave private scratch: 16 rows x 68 f32 (stride 272B, 16B-aligned) = 4352B
    float* scr = (float*)&As[0][0] + (size_t)wave * 1088;

    #pragma unroll
    for (int i = 0; i < 4; ++i) {
        // write fragments: local row = quad*4 + r (0..15), local col = j*16 + l15
        #pragma unroll
        for (int j = 0; j < 4; ++j)
            #pragma unroll
            for (int r = 0; r < 4; ++r) {
                const float y = acc[i][j][r] + bv[j];
                scr[(quad * 4 + r) * 68 + j * 16 + l15] = y / (1.0f + fabsf(y));
            }
        // read back row-linear (wave-private -> no barrier; compiler inserts
        // lgkmcnt for the LDS RAW): per instr = 4 rows x 256B dense stores
        #pragma unroll
        for (int ri = 0; ri < 4; ++ri) {
            const int lr = ri * 4 + quad;      // local row 0..15
            const float4 vv = *(const float4*)&scr[lr * 68 + l15 * 4];
            *(float4*)&ob[(size_t)(wm + i * 16 + lr) * DIM + wn + l15 * 4] = vv;
        }
    }
}

extern "C" void kernel_launch(void* const* d_in, const int* in_sizes, int n_in,
                              void* d_out, int out_size, void* d_ws, size_t ws_size,
                              hipStream_t stream) {
    const float* x       = (const float*)d_in[0];
    const int*   day_ids = (const int*)  d_in[1];
    const float* W       = (const float*)d_in[2];
    const float* bias    = (const float*)d_in[3];
    float*       out     = (float*)d_out;
    __bf16*      Wt      = (__bf16*)d_ws;   // 24*512*512*2 = 12.58 MB

    dim3 tgrid(DIM / 32, DIM / 32, NDAYS);  // (16,16,24)
    transpose_w_kernel<<<tgrid, 256, 0, stream>>>(W, Wt);

    day_adapter_kernel<<<dim3(2048), 256, 0, stream>>>(x, day_ids, Wt, bias, out);
}